// Round 1
// baseline (5660.440 us; speedup 1.0000x reference)
//
#include <hip/hip_runtime.h>
#include <stdint.h>

typedef unsigned int u32;
typedef unsigned long long u64;

#define IMGF 800.0f
#define NPRE 3000
#define NPOST 300
#define NPIX 2500
#define NANCH 22500
#define CIN 1024

// ---------------- ws layout (bytes) ----------------
#define WS_H       0ull            // 512*2500*4      = 5,120,000
#define WS_LOCS    5120000ull      // 36*2500*4       = 360,000
#define WS_SCORES  5480000ull      // 18*2500*4       = 180,000
#define WS_ROI     5660000ull      // 22500*4*4       = 360,000
#define WS_KEYS    6020000ull      // 22500*8         = 180,000
#define WS_CTRL    6200000ull      // 256 (cnt @0, T @8)
#define WS_SKEYS   6200256ull      // 4096*8          = 32,768
#define WS_BOXES   6233024ull      // 3008*4*4        = 48,128
#define WS_VALIDW  6281152ull      // 64*8            = 512
#define WS_MASK    6281664ull      // 141,440*8       = 1,131,520 (padded for prefetch overrun)
#define WS_ROIS    7413184ull      // 300*4*4         = 4,800
#define WS_WT      7417984ull      // 9216*512*4      = 18,874,368
#define WS_FEATT   26292352ull     // 2500*1024*4     = 10,240,000
#define WS_POOLED  36532352ull     // 300*50176*4     = 60,211,200
#define WS_H1      96743552ull     // 300*4096*4      = 4,915,200
#define WS_H2      101658752ull    // 300*4096*4      = 4,915,200
// total ~106.6 MB

__device__ inline u64 shfl64(u64 v, int lane) {
  u32 lo = __shfl((u32)v, lane, 64);
  u32 hi = __shfl((u32)(v >> 32), lane, 64);
  return ((u64)hi << 32) | lo;
}

// ---------------- generic 32x32 transpose: in(R,C) -> out(C,R) ----------------
__global__ __launch_bounds__(256) void k_transpose(const float* __restrict__ in,
        float* __restrict__ out, int R, int C) {
  __shared__ float tile[32][33];
  int c0 = blockIdx.x * 32, r0 = blockIdx.y * 32;
  int tx = threadIdx.x, ty = threadIdx.y;
#pragma unroll
  for (int i = 0; i < 4; ++i) {
    int r = r0 + ty + i * 8, c = c0 + tx;
    if (r < R && c < C) tile[ty + i * 8][tx] = in[(u64)r * C + c];
  }
  __syncthreads();
#pragma unroll
  for (int i = 0; i < 4; ++i) {
    int c = c0 + ty + i * 8, r = r0 + tx;
    if (r < R && c < C) out[(u64)c * R + r] = tile[tx][ty + i * 8];
  }
}

// ---------------- 3x3 SAME conv 1024->512 + bias + relu ----------------
// Wt: (9216, 512) with row k = c*9 + tap ; feat: (1024, 2500) ; h: (512, 2500)
__global__ __launch_bounds__(256) void k_conv3x3(const float* __restrict__ Wt,
        const float* __restrict__ feat, const float* __restrict__ bias,
        float* __restrict__ h) {
  __shared__ float As[16][64];
  __shared__ float Bs[16][64];
  int tid = threadIdx.x;
  int p0 = blockIdx.x * 64;
  int oc0 = blockIdx.y * 64;
  int tr = tid >> 4, tc = tid & 15;
  float acc[4][4] = {};
  double accd[4][4] = {};
  int flush = 0;
  for (int tap = 0; tap < 9; ++tap) {
    int ky = tap / 3 - 1, kx = tap % 3 - 1;
    for (int c0 = 0; c0 < CIN; c0 += 16) {
#pragma unroll
      for (int i = 0; i < 4; ++i) {
        int e = tid + i * 256;
        int cl = e >> 6, oc = e & 63;
        As[cl][oc] = Wt[(u64)((c0 + cl) * 9 + tap) * 512 + oc0 + oc];
      }
#pragma unroll
      for (int i = 0; i < 4; ++i) {
        int e = tid + i * 256;
        int cl = e >> 6, pl = e & 63;
        int p = p0 + pl;
        float v = 0.f;
        if (p < NPIX) {
          int y = p / 50 + ky, x = p % 50 + kx;
          if (y >= 0 && y < 50 && x >= 0 && x < 50)
            v = feat[(c0 + cl) * NPIX + y * 50 + x];
        }
        Bs[cl][pl] = v;
      }
      __syncthreads();
#pragma unroll
      for (int kk = 0; kk < 16; ++kk) {
        float a[4], b[4];
#pragma unroll
        for (int x = 0; x < 4; ++x) a[x] = As[kk][tr * 4 + x];
#pragma unroll
        for (int x = 0; x < 4; ++x) b[x] = Bs[kk][tc * 4 + x];
#pragma unroll
        for (int x = 0; x < 4; ++x)
#pragma unroll
          for (int y = 0; y < 4; ++y)
            acc[x][y] = fmaf(a[x], b[y], acc[x][y]);
      }
      __syncthreads();
      // flush fp32 partials into fp64 every 2 k-tiles (32 channels) to keep
      // accumulation error ~1e-7 (score ordering feeds argsort/NMS!)
      if ((++flush & 1) == 0) {
#pragma unroll
        for (int x = 0; x < 4; ++x)
#pragma unroll
          for (int y = 0; y < 4; ++y) { accd[x][y] += (double)acc[x][y]; acc[x][y] = 0.f; }
      }
    }
  }
#pragma unroll
  for (int x = 0; x < 4; ++x)
#pragma unroll
    for (int y = 0; y < 4; ++y) accd[x][y] += (double)acc[x][y];
#pragma unroll
  for (int x = 0; x < 4; ++x) {
    int oc = oc0 + tr * 4 + x;
#pragma unroll
    for (int y = 0; y < 4; ++y) {
      int p = p0 + tc * 4 + y;
      if (p < NPIX) {
        float v = (float)accd[x][y] + bias[oc];
        h[oc * NPIX + p] = v > 0.f ? v : 0.f;
      }
    }
  }
}

// ---------------- 1x1 convs (rpn loc + score), fp64 accumulate ----------------
__global__ __launch_bounds__(256) void k_rpn1x1(const float* __restrict__ h,
        const float* __restrict__ W_loc, const float* __restrict__ b_loc,
        const float* __restrict__ W_score, const float* __restrict__ b_score,
        float* __restrict__ locs, float* __restrict__ scores) {
  __shared__ float Hs[128][64];
  __shared__ float Ws[16][128];
  int tid = threadIdx.x;
  int p0 = blockIdx.x * 64;
  int o0 = blockIdx.y * 16;
  int pl = tid & 63, og = tid >> 6;
  double acc[4] = {0, 0, 0, 0};
  for (int kc = 0; kc < 512; kc += 128) {
#pragma unroll
    for (int i = 0; i < 32; ++i) {
      int e = tid + i * 256;
      int kl = e >> 6, ppl = e & 63;
      int p = p0 + ppl;
      Hs[kl][ppl] = (p < NPIX) ? h[(kc + kl) * NPIX + p] : 0.f;
    }
#pragma unroll
    for (int i = 0; i < 8; ++i) {
      int e = tid + i * 256;
      int ol = e >> 7, kl = e & 127;
      int o = o0 + ol;
      float w = 0.f;
      if (o < 36) w = W_loc[o * 512 + kc + kl];
      else if (o < 54) w = W_score[(o - 36) * 512 + kc + kl];
      Ws[ol][kl] = w;
    }
    __syncthreads();
#pragma unroll
    for (int oo = 0; oo < 4; ++oo) {
      int ol = og * 4 + oo;
      double a = acc[oo];
      for (int kk = 0; kk < 128; ++kk)
        a = fma((double)Hs[kk][pl], (double)Ws[ol][kk], a);
      acc[oo] = a;
    }
    __syncthreads();
  }
  int p = p0 + pl;
  if (p < NPIX) {
#pragma unroll
    for (int oo = 0; oo < 4; ++oo) {
      int o = o0 + og * 4 + oo;
      if (o < 36) locs[o * NPIX + p] = (float)acc[oo] + b_loc[o];
      else if (o < 54) scores[(o - 36) * NPIX + p] = (float)acc[oo] + b_score[o - 36];
    }
  }
}

// ---------------- decode proposals + keys + rpn outputs ----------------
__global__ __launch_bounds__(256) void k_decode(const float* __restrict__ locs,
        const float* __restrict__ scores, float* __restrict__ roi,
        u64* __restrict__ keys, float* __restrict__ out) {
  int g = blockIdx.x * 256 + threadIdx.x;
  if (g >= NANCH) return;
  int a = g / NPIX, p = g % NPIX;
  int px = p % 50, py = p / 50;
  int n = p * 9 + a;
  const float scl[3] = {8.f, 16.f, 32.f};
  const float rat[3] = {0.5f, 1.f, 2.f};
  float scale = scl[a % 3], ratio = rat[a / 3];
  float ahs = 16.f * scale * sqrtf(ratio);
  float aws = 16.f * scale * sqrtf(1.f / ratio);
  float a0 = rintf(-ahs * 0.5f) + (float)(px * 16);
  float a1 = rintf(-aws * 0.5f) + (float)(py * 16);
  float a2 = rintf(ahs * 0.5f) + (float)(px * 16);
  float a3 = rintf(aws * 0.5f) + (float)(py * 16);
  float awr = a2 - a0, ahr = a3 - a1;             // exact small ints
  float cx = a0 + 0.5f * awr, cy = a1 + 0.5f * ahr;
  float dx = locs[(a * 4 + 0) * NPIX + p];
  float dy = locs[(a * 4 + 1) * NPIX + p];
  float dw = locs[(a * 4 + 2) * NPIX + p];
  float dh = locs[(a * 4 + 3) * NPIX + p];
  float ctr_x = __fadd_rn(__fmul_rn(dx, awr), cx);
  float ctr_y = __fadd_rn(__fmul_rn(dy, ahr), cy);
  float w = __fmul_rn(expf(dw), awr);
  float hh = __fmul_rn(expf(dh), ahr);
  float x1 = fminf(fmaxf(__fsub_rn(ctr_x, __fmul_rn(0.5f, w)), 0.f), IMGF);
  float x2 = fminf(fmaxf(__fadd_rn(ctr_x, __fmul_rn(0.5f, w)), 0.f), IMGF);
  float y1 = fminf(fmaxf(__fsub_rn(ctr_y, __fmul_rn(0.5f, hh)), 0.f), IMGF);
  float y2 = fminf(fmaxf(__fadd_rn(ctr_y, __fmul_rn(0.5f, hh)), 0.f), IMGF);
  bool valid = (__fsub_rn(x2, x1) >= 16.f) && (__fsub_rn(y2, y1) >= 16.f);
  float s0 = scores[(a * 2 + 0) * NPIX + p];
  float s1 = scores[(a * 2 + 1) * NPIX + p];
  float m = fmaxf(s0, s1);
  float e0 = expf(__fsub_rn(s0, m)), e1 = expf(__fsub_rn(s1, m));
  float fg = e1 / __fadd_rn(e0, e1);
  float sc = valid ? fg : -INFINITY;
  u32 ub = __float_as_uint(sc);
  u32 ord = (ub & 0x80000000u) ? ~ub : (ub | 0x80000000u);
  keys[n] = ((u64)ord << 32) | (u32)(NANCH - 1 - n);   // stable: score desc, idx asc
  roi[n * 4 + 0] = x1; roi[n * 4 + 1] = y1; roi[n * 4 + 2] = x2; roi[n * 4 + 3] = y2;
  float* rl = out + 31500;
  rl[n * 4 + 0] = dx; rl[n * 4 + 1] = dy; rl[n * 4 + 2] = dw; rl[n * 4 + 3] = dh;
  float* rs = out + 121500;
  rs[n * 2 + 0] = s0; rs[n * 2 + 1] = s1;
}

// ---------------- exact radix select of 3000th-largest 64-bit key ----------------
__global__ __launch_bounds__(1024) void k_select(const u64* __restrict__ keys,
                                                 u64* __restrict__ ctrlT) {
  __shared__ u32 hist[256];
  __shared__ u64 sprefix;
  __shared__ int sr;
  int tid = threadIdx.x;
  if (tid == 0) { sprefix = 0; sr = NPRE; }
  __syncthreads();
  for (int phase = 7; phase >= 0; --phase) {
    if (tid < 256) hist[tid] = 0;
    __syncthreads();
    u64 prefix = sprefix;
    int shift = phase * 8;
    for (int g = tid; g < NANCH; g += 1024) {
      u64 k = keys[g];
      bool cond = (phase == 7) || ((k >> (shift + 8)) == (prefix >> (shift + 8)));
      if (cond) atomicAdd(&hist[(u32)(k >> shift) & 255u], 1u);
    }
    __syncthreads();
    if (tid == 0) {
      int r = sr;
      u32 cum = 0;
      for (int b = 255; b >= 0; --b) {
        u32 c = hist[b];
        if (cum + c >= (u32)r) { sprefix = prefix | ((u64)b << shift); sr = r - (int)cum; break; }
        cum += c;
      }
    }
    __syncthreads();
  }
  if (tid == 0) *ctrlT = sprefix;
}

__global__ void k_compact(const u64* __restrict__ keys, const u64* __restrict__ ctrlT,
                          u32* __restrict__ cnt, u64* __restrict__ skeys) {
  int g = blockIdx.x * 256 + threadIdx.x;
  if (g >= NANCH) return;
  u64 k = keys[g];
  if (k >= *ctrlT) { u32 i = atomicAdd(cnt, 1u); skeys[i] = k; }
}

// ---------------- single-block bitonic sort (desc) + gather boxes/valid ----------------
__global__ __launch_bounds__(1024) void k_sortgather(const u64* __restrict__ skeys,
        const float* __restrict__ roi, float* __restrict__ boxes, u64* __restrict__ validw) {
  __shared__ u64 s[4096];
  int tid = threadIdx.x;
  for (int i = tid; i < 4096; i += 1024) s[i] = skeys[i];
  __syncthreads();
  for (int k = 2; k <= 4096; k <<= 1) {
    for (int j = k >> 1; j > 0; j >>= 1) {
      for (int i = tid; i < 4096; i += 1024) {
        int ixj = i ^ j;
        if (ixj > i) {
          u64 x = s[i], y = s[ixj];
          bool up = (i & k) == 0;
          if (up ? (x < y) : (x > y)) { s[i] = y; s[ixj] = x; }
        }
      }
      __syncthreads();
    }
  }
  for (int i = tid; i < 4096; i += 1024) {
    bool vl = false;
    if (i < NPRE) {
      u64 key = s[i];
      int n = NANCH - 1 - (int)(u32)(key & 0xFFFFFFFFull);
      boxes[i * 4 + 0] = roi[n * 4 + 0];
      boxes[i * 4 + 1] = roi[n * 4 + 1];
      boxes[i * 4 + 2] = roi[n * 4 + 2];
      boxes[i * 4 + 3] = roi[n * 4 + 3];
      vl = ((u32)(key >> 32)) != 0x007FFFFFu;   // ord(-inf)
    }
    u64 bal = __ballot(vl);
    int w = i >> 6;
    if ((tid & 63) == 0 && w < 47) validw[w] = bal;
  }
}

// ---------------- IoU suppression bitmask (j > i, iou > 0.7) ----------------
__global__ __launch_bounds__(256) void k_mask(const float* __restrict__ boxes,
                                              u64* __restrict__ mask) {
  __shared__ float4 jb[256];
  int tid = threadIdx.x;
  int jstart = blockIdx.y * 256;
  {
    int j = jstart + tid;
    float4 v = make_float4(0, 0, 0, 0);
    if (j < NPRE) v = ((const float4*)boxes)[j];
    jb[tid] = v;
  }
  __syncthreads();
  int i = blockIdx.x * 64 + (tid & 63);
  int wl = tid >> 6;
  int w = blockIdx.y * 4 + wl;
  if (i >= NPRE || w >= 47) return;
  float4 bi = ((const float4*)boxes)[i];
  float areai = __fmul_rn(__fsub_rn(bi.z, bi.x), __fsub_rn(bi.w, bi.y));
  u64 bits = 0;
  for (int b = 0; b < 64; ++b) {
    int j = w * 64 + b;
    if (j < NPRE && j > i) {
      float4 bj = jb[wl * 64 + b];
      float tlx = fmaxf(bi.x, bj.x), tly = fmaxf(bi.y, bj.y);
      float brx = fminf(bi.z, bj.z), bry = fminf(bi.w, bj.w);
      float iw = fmaxf(__fsub_rn(brx, tlx), 0.f);
      float ih = fmaxf(__fsub_rn(bry, tly), 0.f);
      float inter = __fmul_rn(iw, ih);
      float areaj = __fmul_rn(__fsub_rn(bj.z, bj.x), __fsub_rn(bj.w, bj.y));
      float den = __fadd_rn(__fsub_rn(__fadd_rn(areai, areaj), inter), 1e-9f);
      float iou = inter / den;
      if (iou > 0.7f) bits |= (1ull << b);
    }
  }
  mask[(u64)i * 47 + w] = bits;
}

// ---------------- sequential NMS scan (1 wave), early exit at 300 kept ----------------
__global__ __launch_bounds__(64) void k_nms(const u64* __restrict__ mask,
        const u64* __restrict__ validw, const float* __restrict__ boxes,
        float* __restrict__ rois) {
  __shared__ u64 buf[2][1504];   // 32 rows x 47 words, double-buffered
  __shared__ int sel[NPOST];
  int t = threadIdx.x;
  u64 keep = (t < 47) ? validw[t] : 0ull;
#pragma unroll
  for (int u = 0; u < 24; ++u) {
    int idx = u * 64 + t;
    if (idx < 1504) buf[0][idx] = mask[idx];
  }
  int cnt = 0;
  for (int c = 0; c < 94; ++c) {
    if (cnt >= NPOST) break;
    u64 r[24];
    const bool hasnext = (c + 1 < 94);
    const u64* src = mask + (u64)(c + 1) * 1504;
#pragma unroll
    for (int u = 0; u < 24; ++u) r[u] = hasnext ? src[u * 64 + t] : 0ull;
    int rbase = c * 32;
    int cur = c & 1;
#pragma unroll 1
    for (int rr = 0; rr < 32; ++rr) {
      int i = rbase + rr;
      if (i >= NPRE) break;
      u64 kw = shfl64(keep, i >> 6);
      if ((kw >> (i & 63)) & 1ull) {
        if (t == 0) sel[cnt] = i;
        cnt++;
        u64 mrow = (t < 47) ? buf[cur][rr * 47 + t] : 0ull;
        keep &= ~mrow;
        if (cnt >= NPOST) break;
      }
    }
#pragma unroll
    for (int u = 0; u < 24; ++u) {
      int idx = u * 64 + t;
      if (idx < 1504) buf[1 - cur][idx] = r[u];
    }
  }
  __syncthreads();
  for (int q = t; q < NPOST; q += 64) {
    float4 v = make_float4(0, 0, 0, 0);
    if (q < cnt) v = ((const float4*)boxes)[sel[q]];
    ((float4*)rois)[q] = v;
  }
}

// ---------------- ROI align: pooled (300, 1024, 7, 7) ----------------
__global__ __launch_bounds__(256) void k_roialign(const float* __restrict__ rois,
        const float* __restrict__ featT, float* __restrict__ pooled) {
  __shared__ float pb[49][128];
  __shared__ float rb[4];
  int bid = blockIdx.x;
  int r = bid >> 3, cc = (bid & 7) * 128;
  int tid = threadIdx.x;
  if (tid < 4) rb[tid] = rois[r * 4 + tid];
  __syncthreads();
  float x1 = rb[0] / 16.f, y1 = rb[1] / 16.f, x2 = rb[2] / 16.f, y2 = rb[3] / 16.f;
  float bw = fmaxf(__fsub_rn(x2, x1), 1.f) / 7.f;
  float bh = fmaxf(__fsub_rn(y2, y1), 1.f) / 7.f;
  int c = cc + (tid & 127);
  for (int s = (tid >> 7); s < 49; s += 2) {
    int pyy = s / 7, pxx = s % 7;
    float X = __fadd_rn(x1, __fmul_rn((float)pxx + 0.5f, bw));
    float Y = __fadd_rn(y1, __fmul_rn((float)pyy + 0.5f, bh));
    float x0f = floorf(X), y0f = floorf(Y);
    int x0i = min(max((int)x0f, 0), 49);
    int x1i = min(x0i + 1, 49);
    int y0i = min(max((int)y0f, 0), 49);
    int y1i = min(y0i + 1, 49);
    float wx = __fsub_rn(X, x0f), wy = __fsub_rn(Y, y0f);
    float omwx = __fsub_rn(1.f, wx), omwy = __fsub_rn(1.f, wy);
    float v00 = featT[(y0i * 50 + x0i) * 1024 + c];
    float v01 = featT[(y0i * 50 + x1i) * 1024 + c];
    float v10 = featT[(y1i * 50 + x0i) * 1024 + c];
    float v11 = featT[(y1i * 50 + x1i) * 1024 + c];
    float t0 = __fmul_rn(__fmul_rn(v00, omwy), omwx);
    float t1 = __fmul_rn(__fmul_rn(v01, omwy), wx);
    float t2 = __fmul_rn(__fmul_rn(v10, wy), omwx);
    float t3 = __fmul_rn(__fmul_rn(v11, wy), wx);
    pb[s][tid & 127] = __fadd_rn(__fadd_rn(__fadd_rn(t0, t1), t2), t3);
  }
  __syncthreads();
  for (int e = tid; e < 49 * 128; e += 256) {
    int cl = e / 49, s2 = e % 49;
    pooled[(u64)r * 50176 + (u64)(cc + cl) * 49 + s2] = pb[s2][cl];
  }
}

// ---------------- fp32 GEMM, split-K with atomic accumulate ----------------
#define GBM 128
#define GBN 64
#define GBK 16
__global__ __launch_bounds__(256) void k_gemm_splitk(const float* __restrict__ A,
        const float* __restrict__ B, float* __restrict__ C,
        int M, int N, int K, int kseglen) {
  __shared__ float As[GBK][GBM + 4];
  __shared__ float Bs[GBK][GBN];
  int tid = threadIdx.x;
  int m0 = blockIdx.x * GBM;
  int n0 = blockIdx.y * GBN;
  int k0 = blockIdx.z * kseglen;
  int kend = k0 + kseglen;
  int row_l = (tid >> 4) * 8;
  int col_l = (tid & 15) * 4;
  float acc[8][4] = {};
  for (int kt = k0; kt < kend; kt += GBK) {
#pragma unroll
    for (int i = 0; i < 8; ++i) {
      int e = tid + i * 256;
      int ml = e >> 4, kl = e & 15;
      int m = m0 + ml;
      As[kl][ml] = (m < M) ? A[(u64)m * K + kt + kl] : 0.f;
    }
#pragma unroll
    for (int i = 0; i < 4; ++i) {
      int e = tid + i * 256;
      int kl = e >> 6, nl = e & 63;
      Bs[kl][nl] = B[(u64)(kt + kl) * N + n0 + nl];
    }
    __syncthreads();
#pragma unroll
    for (int kk = 0; kk < GBK; ++kk) {
      float a[8], b[4];
#pragma unroll
      for (int x = 0; x < 8; ++x) a[x] = As[kk][row_l + x];
#pragma unroll
      for (int y = 0; y < 4; ++y) b[y] = Bs[kk][col_l + y];
#pragma unroll
      for (int x = 0; x < 8; ++x)
#pragma unroll
        for (int y = 0; y < 4; ++y)
          acc[x][y] = fmaf(a[x], b[y], acc[x][y]);
    }
    __syncthreads();
  }
#pragma unroll
  for (int x = 0; x < 8; ++x) {
    int m = m0 + row_l + x;
    if (m < M) {
#pragma unroll
      for (int y = 0; y < 4; ++y)
        atomicAdd(&C[(u64)m * N + n0 + col_l + y], acc[x][y]);
    }
  }
}

__global__ void k_bias_relu(float* __restrict__ X, const float* __restrict__ bias,
                            int total, int Nmask) {
  int g = blockIdx.x * 256 + threadIdx.x;
  if (g < total) {
    float v = X[g] + bias[g & Nmask];
    X[g] = v > 0.f ? v : 0.f;
  }
}

// ---------------- final heads: (300x84)+(300x21) from h2 ----------------
__global__ __launch_bounds__(128) void k_heads(const float* __restrict__ h2,
        const float* __restrict__ W_reg, const float* __restrict__ b_reg,
        const float* __restrict__ W_cls, const float* __restrict__ b_cls,
        float* __restrict__ out) {
  __shared__ float hrow[4096];
  int m = blockIdx.x;
  int tid = threadIdx.x;
  for (int e = tid; e < 4096; e += 128) hrow[e] = h2[(u64)m * 4096 + e];
  __syncthreads();
  int n = tid;
  if (n < 105) {
    const float* W; int ld, nn;
    if (n < 84) { W = W_reg; ld = 84; nn = n; }
    else { W = W_cls; ld = 21; nn = n - 84; }
    float acc = 0.f;
    for (int k = 0; k < 4096; ++k)
      acc = fmaf(hrow[k], W[(u64)k * ld + nn], acc);
    if (n < 84) out[m * 84 + n] = acc + b_reg[n];
    else out[25200 + m * 21 + nn] = acc + b_cls[nn];
  }
}

extern "C" void kernel_launch(void* const* d_in, const int* in_sizes, int n_in,
                              void* d_out, int out_size, void* d_ws, size_t ws_size,
                              hipStream_t stream) {
  (void)in_sizes; (void)n_in; (void)out_size; (void)ws_size;
  const float* features = (const float*)d_in[0];
  const float* W_conv   = (const float*)d_in[1];
  const float* b_conv   = (const float*)d_in[2];
  const float* W_loc    = (const float*)d_in[3];
  const float* b_loc    = (const float*)d_in[4];
  const float* W_score  = (const float*)d_in[5];
  const float* b_score  = (const float*)d_in[6];
  const float* W_fc1    = (const float*)d_in[7];
  const float* b_fc1    = (const float*)d_in[8];
  const float* W_fc2    = (const float*)d_in[9];
  const float* b_fc2    = (const float*)d_in[10];
  const float* W_cls    = (const float*)d_in[11];
  const float* b_cls    = (const float*)d_in[12];
  const float* W_reg    = (const float*)d_in[13];
  const float* b_reg    = (const float*)d_in[14];

  char* ws = (char*)d_ws;
  float* out    = (float*)d_out;
  float* h      = (float*)(ws + WS_H);
  float* locs   = (float*)(ws + WS_LOCS);
  float* scores = (float*)(ws + WS_SCORES);
  float* roi    = (float*)(ws + WS_ROI);
  u64*   keys   = (u64*)(ws + WS_KEYS);
  u32*   cnt    = (u32*)(ws + WS_CTRL);
  u64*   ctrlT  = (u64*)(ws + WS_CTRL + 8);
  u64*   skeys  = (u64*)(ws + WS_SKEYS);
  float* boxes  = (float*)(ws + WS_BOXES);
  u64*   validw = (u64*)(ws + WS_VALIDW);
  u64*   mask   = (u64*)(ws + WS_MASK);
  float* rois   = (float*)(ws + WS_ROIS);
  float* Wt     = (float*)(ws + WS_WT);
  float* featT  = (float*)(ws + WS_FEATT);
  float* pooled = (float*)(ws + WS_POOLED);
  float* h1     = (float*)(ws + WS_H1);
  float* h2     = (float*)(ws + WS_H2);

  hipMemsetAsync(ws + WS_CTRL, 0, 256, stream);
  hipMemsetAsync(ws + WS_SKEYS, 0, 4096 * 8, stream);
  hipMemsetAsync(ws + WS_H1, 0, 300 * 4096 * 4, stream);
  hipMemsetAsync(ws + WS_H2, 0, 300 * 4096 * 4, stream);

  k_transpose<<<dim3(288, 16), dim3(32, 8), 0, stream>>>(W_conv, Wt, 512, 9216);
  k_transpose<<<dim3(79, 32),  dim3(32, 8), 0, stream>>>(features, featT, 1024, 2500);
  k_conv3x3<<<dim3(40, 8), 256, 0, stream>>>(Wt, features, b_conv, h);
  k_rpn1x1<<<dim3(40, 4), 256, 0, stream>>>(h, W_loc, b_loc, W_score, b_score, locs, scores);
  k_decode<<<dim3(88), 256, 0, stream>>>(locs, scores, roi, keys, out);
  k_select<<<1, 1024, 0, stream>>>(keys, ctrlT);
  k_compact<<<88, 256, 0, stream>>>(keys, ctrlT, cnt, skeys);
  k_sortgather<<<1, 1024, 0, stream>>>(skeys, roi, boxes, validw);
  k_mask<<<dim3(47, 12), 256, 0, stream>>>(boxes, mask);
  k_nms<<<1, 64, 0, stream>>>(mask, validw, boxes, rois);
  k_roialign<<<2400, 256, 0, stream>>>(rois, featT, pooled);
  k_gemm_splitk<<<dim3(3, 64, 4), 256, 0, stream>>>(pooled, W_fc1, h1, 300, 4096, 50176, 12544);
  k_bias_relu<<<4800, 256, 0, stream>>>(h1, b_fc1, 300 * 4096, 4095);
  k_gemm_splitk<<<dim3(3, 64, 4), 256, 0, stream>>>(h1, W_fc2, h2, 300, 4096, 4096, 1024);
  k_bias_relu<<<4800, 256, 0, stream>>>(h2, b_fc2, 300 * 4096, 4095);
  k_heads<<<300, 128, 0, stream>>>(h2, W_reg, b_reg, W_cls, b_cls, out);
}

// Round 2
// 3193.787 us; speedup vs baseline: 1.7723x; 1.7723x over previous
//
#include <hip/hip_runtime.h>
#include <stdint.h>

typedef unsigned int u32;
typedef unsigned long long u64;
typedef unsigned short u16;
typedef __attribute__((ext_vector_type(4))) float f32x4;
typedef __attribute__((ext_vector_type(8))) short s16x8;
typedef __attribute__((ext_vector_type(4))) u32 u32x4;

#define IMGF 800.0f
#define NPRE 3000
#define NPOST 300
#define NPIX 2500
#define NANCH 22500
#define CIN 1024

// ---------------- ws layout (bytes) ----------------
#define WS_H       0ull            // 512*2500*4      = 5,120,000
#define WS_LOCS    5120000ull
#define WS_SCORES  5480000ull
#define WS_ROI     5660000ull
#define WS_KEYS    6020000ull
#define WS_CTRL    6200000ull
#define WS_SKEYS   6200256ull
#define WS_BOXES   6233024ull
#define WS_VALIDW  6281152ull
#define WS_MASK    6281664ull
#define WS_ROIS    7413184ull
#define WS_WT      7417984ull      // 9216*512*4 = 18,874,368
#define WS_FEATT   26292352ull     // 2500*1024*4 = 10,240,000
#define WS_PH      36532352ull     // pooled hi bf16: 300*50176*2 = 30,105,600
#define WS_PL      66637952ull     // pooled lo bf16: 30,105,600 (ends 96,743,552)
#define WS_CACC    96743552ull     // fp32 accumulator 300*4096*4 = 4,915,200 (ends 101,658,752)
// h1/h2 bf16 planes alias into the PH region (PH is dead after fc1 GEMM):
#define WS_H1H     36532352ull
#define WS_H1L     38989952ull
#define WS_H2H     41447552ull
#define WS_H2L     43905152ull
// total ws high-water: 101.66 MB (<= round-0's 106.6 MB)

__device__ inline u64 shfl64(u64 v, int lane) {
  u32 lo = __shfl((u32)v, lane, 64);
  u32 hi = __shfl((u32)(v >> 32), lane, 64);
  return ((u64)hi << 32) | lo;
}

// round-to-nearest-even fp32 -> bf16 hi/lo split
__device__ inline void bsplit(float x, u16& h, u16& l) {
  u32 u = __float_as_uint(x);
  u32 rh = u + 0x7FFFu + ((u >> 16) & 1u);
  h = (u16)(rh >> 16);
  float hf = __uint_as_float(((u32)h) << 16);
  float lf = __fsub_rn(x, hf);
  u32 v = __float_as_uint(lf);
  u32 rl = v + 0x7FFFu + ((v >> 16) & 1u);
  l = (u16)(rl >> 16);
}
__device__ inline float bf2f(u16 b) { return __uint_as_float(((u32)b) << 16); }

// ---------------- generic 32x32 transpose: in(R,C) -> out(C,R) ----------------
__global__ __launch_bounds__(256) void k_transpose(const float* __restrict__ in,
        float* __restrict__ out, int R, int C) {
  __shared__ float tile[32][33];
  int c0 = blockIdx.x * 32, r0 = blockIdx.y * 32;
  int tx = threadIdx.x, ty = threadIdx.y;
#pragma unroll
  for (int i = 0; i < 4; ++i) {
    int r = r0 + ty + i * 8, c = c0 + tx;
    if (r < R && c < C) tile[ty + i * 8][tx] = in[(u64)r * C + c];
  }
  __syncthreads();
#pragma unroll
  for (int i = 0; i < 4; ++i) {
    int c = c0 + ty + i * 8, r = r0 + tx;
    if (r < R && c < C) out[(u64)c * R + r] = tile[tx][ty + i * 8];
  }
}

// ---------------- 3x3 SAME conv 1024->512 + bias + relu (score path: fp64 flush) ----
__global__ __launch_bounds__(256) void k_conv3x3(const float* __restrict__ Wt,
        const float* __restrict__ feat, const float* __restrict__ bias,
        float* __restrict__ h) {
  __shared__ float As[16][64];
  __shared__ float Bs[16][64];
  int tid = threadIdx.x;
  int p0 = blockIdx.x * 64;
  int oc0 = blockIdx.y * 64;
  int tr = tid >> 4, tc = tid & 15;
  float acc[4][4] = {};
  double accd[4][4] = {};
  int flush = 0;
  for (int tap = 0; tap < 9; ++tap) {
    int ky = tap / 3 - 1, kx = tap % 3 - 1;
    for (int c0 = 0; c0 < CIN; c0 += 16) {
#pragma unroll
      for (int i = 0; i < 4; ++i) {
        int e = tid + i * 256;
        int cl = e >> 6, oc = e & 63;
        As[cl][oc] = Wt[(u64)((c0 + cl) * 9 + tap) * 512 + oc0 + oc];
      }
#pragma unroll
      for (int i = 0; i < 4; ++i) {
        int e = tid + i * 256;
        int cl = e >> 6, pl = e & 63;
        int p = p0 + pl;
        float v = 0.f;
        if (p < NPIX) {
          int y = p / 50 + ky, x = p % 50 + kx;
          if (y >= 0 && y < 50 && x >= 0 && x < 50)
            v = feat[(c0 + cl) * NPIX + y * 50 + x];
        }
        Bs[cl][pl] = v;
      }
      __syncthreads();
#pragma unroll
      for (int kk = 0; kk < 16; ++kk) {
        float a[4], b[4];
#pragma unroll
        for (int x = 0; x < 4; ++x) a[x] = As[kk][tr * 4 + x];
#pragma unroll
        for (int x = 0; x < 4; ++x) b[x] = Bs[kk][tc * 4 + x];
#pragma unroll
        for (int x = 0; x < 4; ++x)
#pragma unroll
          for (int y = 0; y < 4; ++y)
            acc[x][y] = fmaf(a[x], b[y], acc[x][y]);
      }
      __syncthreads();
      if ((++flush & 1) == 0) {
#pragma unroll
        for (int x = 0; x < 4; ++x)
#pragma unroll
          for (int y = 0; y < 4; ++y) { accd[x][y] += (double)acc[x][y]; acc[x][y] = 0.f; }
      }
    }
  }
#pragma unroll
  for (int x = 0; x < 4; ++x)
#pragma unroll
    for (int y = 0; y < 4; ++y) accd[x][y] += (double)acc[x][y];
#pragma unroll
  for (int x = 0; x < 4; ++x) {
    int oc = oc0 + tr * 4 + x;
#pragma unroll
    for (int y = 0; y < 4; ++y) {
      int p = p0 + tc * 4 + y;
      if (p < NPIX) {
        float v = (float)accd[x][y] + bias[oc];
        h[oc * NPIX + p] = v > 0.f ? v : 0.f;
      }
    }
  }
}

// ---------------- 1x1 convs (rpn loc + score), fp64 accumulate ----------------
__global__ __launch_bounds__(256) void k_rpn1x1(const float* __restrict__ h,
        const float* __restrict__ W_loc, const float* __restrict__ b_loc,
        const float* __restrict__ W_score, const float* __restrict__ b_score,
        float* __restrict__ locs, float* __restrict__ scores) {
  __shared__ float Hs[128][64];
  __shared__ float Ws[16][128];
  int tid = threadIdx.x;
  int p0 = blockIdx.x * 64;
  int o0 = blockIdx.y * 16;
  int pl = tid & 63, og = tid >> 6;
  double acc[4] = {0, 0, 0, 0};
  for (int kc = 0; kc < 512; kc += 128) {
#pragma unroll
    for (int i = 0; i < 32; ++i) {
      int e = tid + i * 256;
      int kl = e >> 6, ppl = e & 63;
      int p = p0 + ppl;
      Hs[kl][ppl] = (p < NPIX) ? h[(kc + kl) * NPIX + p] : 0.f;
    }
#pragma unroll
    for (int i = 0; i < 8; ++i) {
      int e = tid + i * 256;
      int ol = e >> 7, kl = e & 127;
      int o = o0 + ol;
      float w = 0.f;
      if (o < 36) w = W_loc[o * 512 + kc + kl];
      else if (o < 54) w = W_score[(o - 36) * 512 + kc + kl];
      Ws[ol][kl] = w;
    }
    __syncthreads();
#pragma unroll
    for (int oo = 0; oo < 4; ++oo) {
      int ol = og * 4 + oo;
      double a = acc[oo];
      for (int kk = 0; kk < 128; ++kk)
        a = fma((double)Hs[kk][pl], (double)Ws[ol][kk], a);
      acc[oo] = a;
    }
    __syncthreads();
  }
  int p = p0 + pl;
  if (p < NPIX) {
#pragma unroll
    for (int oo = 0; oo < 4; ++oo) {
      int o = o0 + og * 4 + oo;
      if (o < 36) locs[o * NPIX + p] = (float)acc[oo] + b_loc[o];
      else if (o < 54) scores[(o - 36) * NPIX + p] = (float)acc[oo] + b_score[o - 36];
    }
  }
}

// ---------------- decode proposals + keys + rpn outputs ----------------
__global__ __launch_bounds__(256) void k_decode(const float* __restrict__ locs,
        const float* __restrict__ scores, float* __restrict__ roi,
        u64* __restrict__ keys, float* __restrict__ out) {
  int g = blockIdx.x * 256 + threadIdx.x;
  if (g >= NANCH) return;
  int a = g / NPIX, p = g % NPIX;
  int px = p % 50, py = p / 50;
  int n = p * 9 + a;
  const float scl[3] = {8.f, 16.f, 32.f};
  const float rat[3] = {0.5f, 1.f, 2.f};
  float scale = scl[a % 3], ratio = rat[a / 3];
  float ahs = 16.f * scale * sqrtf(ratio);
  float aws = 16.f * scale * sqrtf(1.f / ratio);
  float a0 = rintf(-ahs * 0.5f) + (float)(px * 16);
  float a1 = rintf(-aws * 0.5f) + (float)(py * 16);
  float a2 = rintf(ahs * 0.5f) + (float)(px * 16);
  float a3 = rintf(aws * 0.5f) + (float)(py * 16);
  float awr = a2 - a0, ahr = a3 - a1;
  float cx = a0 + 0.5f * awr, cy = a1 + 0.5f * ahr;
  float dx = locs[(a * 4 + 0) * NPIX + p];
  float dy = locs[(a * 4 + 1) * NPIX + p];
  float dw = locs[(a * 4 + 2) * NPIX + p];
  float dh = locs[(a * 4 + 3) * NPIX + p];
  float ctr_x = __fadd_rn(__fmul_rn(dx, awr), cx);
  float ctr_y = __fadd_rn(__fmul_rn(dy, ahr), cy);
  float w = __fmul_rn(expf(dw), awr);
  float hh = __fmul_rn(expf(dh), ahr);
  float x1 = fminf(fmaxf(__fsub_rn(ctr_x, __fmul_rn(0.5f, w)), 0.f), IMGF);
  float x2 = fminf(fmaxf(__fadd_rn(ctr_x, __fmul_rn(0.5f, w)), 0.f), IMGF);
  float y1 = fminf(fmaxf(__fsub_rn(ctr_y, __fmul_rn(0.5f, hh)), 0.f), IMGF);
  float y2 = fminf(fmaxf(__fadd_rn(ctr_y, __fmul_rn(0.5f, hh)), 0.f), IMGF);
  bool valid = (__fsub_rn(x2, x1) >= 16.f) && (__fsub_rn(y2, y1) >= 16.f);
  float s0 = scores[(a * 2 + 0) * NPIX + p];
  float s1 = scores[(a * 2 + 1) * NPIX + p];
  float m = fmaxf(s0, s1);
  float e0 = expf(__fsub_rn(s0, m)), e1 = expf(__fsub_rn(s1, m));
  float fg = e1 / __fadd_rn(e0, e1);
  float sc = valid ? fg : -INFINITY;
  u32 ub = __float_as_uint(sc);
  u32 ord = (ub & 0x80000000u) ? ~ub : (ub | 0x80000000u);
  keys[n] = ((u64)ord << 32) | (u32)(NANCH - 1 - n);
  roi[n * 4 + 0] = x1; roi[n * 4 + 1] = y1; roi[n * 4 + 2] = x2; roi[n * 4 + 3] = y2;
  float* rl = out + 31500;
  rl[n * 4 + 0] = dx; rl[n * 4 + 1] = dy; rl[n * 4 + 2] = dw; rl[n * 4 + 3] = dh;
  float* rs = out + 121500;
  rs[n * 2 + 0] = s0; rs[n * 2 + 1] = s1;
}

// ---------------- exact radix select of 3000th-largest 64-bit key ----------------
__global__ __launch_bounds__(1024) void k_select(const u64* __restrict__ keys,
                                                 u64* __restrict__ ctrlT) {
  __shared__ u32 hist[256];
  __shared__ u64 sprefix;
  __shared__ int sr;
  int tid = threadIdx.x;
  if (tid == 0) { sprefix = 0; sr = NPRE; }
  __syncthreads();
  for (int phase = 7; phase >= 0; --phase) {
    if (tid < 256) hist[tid] = 0;
    __syncthreads();
    u64 prefix = sprefix;
    int shift = phase * 8;
    for (int g = tid; g < NANCH; g += 1024) {
      u64 k = keys[g];
      bool cond = (phase == 7) || ((k >> (shift + 8)) == (prefix >> (shift + 8)));
      if (cond) atomicAdd(&hist[(u32)(k >> shift) & 255u], 1u);
    }
    __syncthreads();
    if (tid == 0) {
      int r = sr;
      u32 cum = 0;
      for (int b = 255; b >= 0; --b) {
        u32 c = hist[b];
        if (cum + c >= (u32)r) { sprefix = prefix | ((u64)b << shift); sr = r - (int)cum; break; }
        cum += c;
      }
    }
    __syncthreads();
  }
  if (tid == 0) *ctrlT = sprefix;
}

__global__ void k_compact(const u64* __restrict__ keys, const u64* __restrict__ ctrlT,
                          u32* __restrict__ cnt, u64* __restrict__ skeys) {
  int g = blockIdx.x * 256 + threadIdx.x;
  if (g >= NANCH) return;
  u64 k = keys[g];
  if (k >= *ctrlT) { u32 i = atomicAdd(cnt, 1u); skeys[i] = k; }
}

// ---------------- single-block bitonic sort (desc) + gather boxes/valid ----------------
__global__ __launch_bounds__(1024) void k_sortgather(const u64* __restrict__ skeys,
        const float* __restrict__ roi, float* __restrict__ boxes, u64* __restrict__ validw) {
  __shared__ u64 s[4096];
  int tid = threadIdx.x;
  for (int i = tid; i < 4096; i += 1024) s[i] = skeys[i];
  __syncthreads();
  for (int k = 2; k <= 4096; k <<= 1) {
    for (int j = k >> 1; j > 0; j >>= 1) {
      for (int i = tid; i < 4096; i += 1024) {
        int ixj = i ^ j;
        if (ixj > i) {
          u64 x = s[i], y = s[ixj];
          bool up = (i & k) == 0;
          if (up ? (x < y) : (x > y)) { s[i] = y; s[ixj] = x; }
        }
      }
      __syncthreads();
    }
  }
  for (int i = tid; i < 4096; i += 1024) {
    bool vl = false;
    if (i < NPRE) {
      u64 key = s[i];
      int n = NANCH - 1 - (int)(u32)(key & 0xFFFFFFFFull);
      boxes[i * 4 + 0] = roi[n * 4 + 0];
      boxes[i * 4 + 1] = roi[n * 4 + 1];
      boxes[i * 4 + 2] = roi[n * 4 + 2];
      boxes[i * 4 + 3] = roi[n * 4 + 3];
      vl = ((u32)(key >> 32)) != 0x007FFFFFu;
    }
    u64 bal = __ballot(vl);
    int w = i >> 6;
    if ((tid & 63) == 0 && w < 47) validw[w] = bal;
  }
}

// ---------------- IoU suppression bitmask (j > i, iou > 0.7) ----------------
__global__ __launch_bounds__(256) void k_mask(const float* __restrict__ boxes,
                                              u64* __restrict__ mask) {
  __shared__ float4 jb[256];
  int tid = threadIdx.x;
  int jstart = blockIdx.y * 256;
  {
    int j = jstart + tid;
    float4 v = make_float4(0, 0, 0, 0);
    if (j < NPRE) v = ((const float4*)boxes)[j];
    jb[tid] = v;
  }
  __syncthreads();
  int i = blockIdx.x * 64 + (tid & 63);
  int wl = tid >> 6;
  int w = blockIdx.y * 4 + wl;
  if (i >= NPRE || w >= 47) return;
  float4 bi = ((const float4*)boxes)[i];
  float areai = __fmul_rn(__fsub_rn(bi.z, bi.x), __fsub_rn(bi.w, bi.y));
  u64 bits = 0;
  for (int b = 0; b < 64; ++b) {
    int j = w * 64 + b;
    if (j < NPRE && j > i) {
      float4 bj = jb[wl * 64 + b];
      float tlx = fmaxf(bi.x, bj.x), tly = fmaxf(bi.y, bj.y);
      float brx = fminf(bi.z, bj.z), bry = fminf(bi.w, bj.w);
      float iw = fmaxf(__fsub_rn(brx, tlx), 0.f);
      float ih = fmaxf(__fsub_rn(bry, tly), 0.f);
      float inter = __fmul_rn(iw, ih);
      float areaj = __fmul_rn(__fsub_rn(bj.z, bj.x), __fsub_rn(bj.w, bj.y));
      float den = __fadd_rn(__fsub_rn(__fadd_rn(areai, areaj), inter), 1e-9f);
      float iou = inter / den;
      if (iou > 0.7f) bits |= (1ull << b);
    }
  }
  mask[(u64)i * 47 + w] = bits;
}

// ---------------- sequential NMS scan (1 wave), early exit at 300 kept ----------------
__global__ __launch_bounds__(64) void k_nms(const u64* __restrict__ mask,
        const u64* __restrict__ validw, const float* __restrict__ boxes,
        float* __restrict__ rois) {
  __shared__ u64 buf[2][1504];
  __shared__ int sel[NPOST];
  int t = threadIdx.x;
  u64 keep = (t < 47) ? validw[t] : 0ull;
#pragma unroll
  for (int u = 0; u < 24; ++u) {
    int idx = u * 64 + t;
    if (idx < 1504) buf[0][idx] = mask[idx];
  }
  int cnt = 0;
  for (int c = 0; c < 94; ++c) {
    if (cnt >= NPOST) break;
    u64 r[24];
    const bool hasnext = (c + 1 < 94);
    const u64* src = mask + (u64)(c + 1) * 1504;
#pragma unroll
    for (int u = 0; u < 24; ++u) r[u] = hasnext ? src[u * 64 + t] : 0ull;
    int rbase = c * 32;
    int cur = c & 1;
#pragma unroll 1
    for (int rr = 0; rr < 32; ++rr) {
      int i = rbase + rr;
      if (i >= NPRE) break;
      u64 kw = shfl64(keep, i >> 6);
      if ((kw >> (i & 63)) & 1ull) {
        if (t == 0) sel[cnt] = i;
        cnt++;
        u64 mrow = (t < 47) ? buf[cur][rr * 47 + t] : 0ull;
        keep &= ~mrow;
        if (cnt >= NPOST) break;
      }
    }
#pragma unroll
    for (int u = 0; u < 24; ++u) {
      int idx = u * 64 + t;
      if (idx < 1504) buf[1 - cur][idx] = r[u];
    }
  }
  __syncthreads();
  for (int q = t; q < NPOST; q += 64) {
    float4 v = make_float4(0, 0, 0, 0);
    if (q < cnt) v = ((const float4*)boxes)[sel[q]];
    ((float4*)rois)[q] = v;
  }
}

// ---------------- ROI align: pooled -> bf16 hi/lo planes [300][50176] ----------------
__global__ __launch_bounds__(256) void k_roialign(const float* __restrict__ rois,
        const float* __restrict__ featT, u16* __restrict__ Phi, u16* __restrict__ Plo) {
  __shared__ float pb[49][128];
  __shared__ float rb[4];
  int bid = blockIdx.x;
  int r = bid >> 3, cc = (bid & 7) * 128;
  int tid = threadIdx.x;
  if (tid < 4) rb[tid] = rois[r * 4 + tid];
  __syncthreads();
  float x1 = rb[0] / 16.f, y1 = rb[1] / 16.f, x2 = rb[2] / 16.f, y2 = rb[3] / 16.f;
  float bw = fmaxf(__fsub_rn(x2, x1), 1.f) / 7.f;
  float bh = fmaxf(__fsub_rn(y2, y1), 1.f) / 7.f;
  int c = cc + (tid & 127);
  for (int s = (tid >> 7); s < 49; s += 2) {
    int pyy = s / 7, pxx = s % 7;
    float X = __fadd_rn(x1, __fmul_rn((float)pxx + 0.5f, bw));
    float Y = __fadd_rn(y1, __fmul_rn((float)pyy + 0.5f, bh));
    float x0f = floorf(X), y0f = floorf(Y);
    int x0i = min(max((int)x0f, 0), 49);
    int x1i = min(x0i + 1, 49);
    int y0i = min(max((int)y0f, 0), 49);
    int y1i = min(y0i + 1, 49);
    float wx = __fsub_rn(X, x0f), wy = __fsub_rn(Y, y0f);
    float omwx = __fsub_rn(1.f, wx), omwy = __fsub_rn(1.f, wy);
    float v00 = featT[(y0i * 50 + x0i) * 1024 + c];
    float v01 = featT[(y0i * 50 + x1i) * 1024 + c];
    float v10 = featT[(y1i * 50 + x0i) * 1024 + c];
    float v11 = featT[(y1i * 50 + x1i) * 1024 + c];
    float t0 = __fmul_rn(__fmul_rn(v00, omwy), omwx);
    float t1 = __fmul_rn(__fmul_rn(v01, omwy), wx);
    float t2 = __fmul_rn(__fmul_rn(v10, wy), omwx);
    float t3 = __fmul_rn(__fmul_rn(v11, wy), wx);
    pb[s][tid & 127] = __fadd_rn(__fadd_rn(__fadd_rn(t0, t1), t2), t3);
  }
  __syncthreads();
  for (int e = tid; e < 49 * 128; e += 256) {
    int cl = e / 49, s2 = e % 49;
    u64 idx = (u64)r * 50176 + (u64)(cc + cl) * 49 + s2;
    u16 hb, lb; bsplit(pb[s2][cl], hb, lb);
    Phi[idx] = hb; Plo[idx] = lb;
  }
}

// ---------------- hi/lo bf16 MFMA GEMM: C += A(Mpad x K) * B(K x N) ----------------
// A given as bf16 hi/lo planes [m][K]; B fp32 [K][N] converted in-kernel.
// 128x128 tile, 4 waves (2x2), 16x16x32 MFMA, 3-pass Markidis, splitK atomics.
__device__ inline u32 swz(u32 row, u32 kblk) {
  return row * 64u + ((kblk ^ ((row >> 1) & 3u)) << 4);
}

__global__ __launch_bounds__(256) void k_gemm_hl(
    const u16* __restrict__ Ah, const u16* __restrict__ Al,
    const float* __restrict__ B, float* __restrict__ C,
    int M, int N, int K, int ksteps) {
  __shared__ char lds[32768];   // planes: Ah 0, Al 8192, Bh 16384, Bl 24576
  int tid = threadIdx.x;
  int m0 = blockIdx.x * 128, n0 = blockIdx.y * 128;
  int kt0 = blockIdx.z * ksteps * 32;
  // A staging: thread -> (row tid>>2 and +64, kblk tid&3), one b128 per plane per row
  int aml = tid >> 2, akb = tid & 3;
  // B staging: thread -> column n0+(tid&127), k-range (tid>>7)*16..+16
  int bnl = tid & 127, bkh = tid >> 7;
  // wave / fragment mapping
  int wid = tid >> 6, lane = tid & 63;
  int wm = (wid >> 1) * 64, wn = (wid & 1) * 64;
  int fr = lane & 15;   // row (A) / col (B) within 16-frag
  int fq = lane >> 4;   // k-block [0,4)

  f32x4 acc[4][4] = {};
  u32x4 ah0, ah1, al0, al1;
  float bv[16];
  const u32x4 zv = {0, 0, 0, 0};

#define LOADA(KT) { \
    int r0 = m0 + aml, r1 = r0 + 64; \
    u64 ko = (u64)(KT) + akb * 8; \
    ah0 = (r0 < M) ? *(const u32x4*)(Ah + (u64)r0 * K + ko) : zv; \
    ah1 = (r1 < M) ? *(const u32x4*)(Ah + (u64)r1 * K + ko) : zv; \
    al0 = (r0 < M) ? *(const u32x4*)(Al + (u64)r0 * K + ko) : zv; \
    al1 = (r1 < M) ? *(const u32x4*)(Al + (u64)r1 * K + ko) : zv; }

#define LOADB(KT) { \
    u64 base = (u64)((KT) + bkh * 16) * N + n0 + bnl; \
    _Pragma("unroll") \
    for (int t = 0; t < 16; ++t) bv[t] = B[base + (u64)t * N]; }

  LOADA(kt0); LOADB(kt0);

  for (int s = 0; s < ksteps; ++s) {
    __syncthreads();
    // ---- store A ----
    *(u32x4*)(lds + swz(aml, akb)) = ah0;
    *(u32x4*)(lds + swz(aml + 64, akb)) = ah1;
    *(u32x4*)(lds + 8192 + swz(aml, akb)) = al0;
    *(u32x4*)(lds + 8192 + swz(aml + 64, akb)) = al1;
    // ---- convert + store B ----
    {
      u32 hw[8], lw[8];
#pragma unroll
      for (int wq = 0; wq < 8; ++wq) {
        u16 h0, l0, h1, l1;
        bsplit(bv[2 * wq], h0, l0);
        bsplit(bv[2 * wq + 1], h1, l1);
        hw[wq] = (u32)h0 | ((u32)h1 << 16);
        lw[wq] = (u32)l0 | ((u32)l1 << 16);
      }
      u32x4 v;
      v = (u32x4){hw[0], hw[1], hw[2], hw[3]};
      *(u32x4*)(lds + 16384 + swz(bnl, bkh * 2)) = v;
      v = (u32x4){hw[4], hw[5], hw[6], hw[7]};
      *(u32x4*)(lds + 16384 + swz(bnl, bkh * 2 + 1)) = v;
      v = (u32x4){lw[0], lw[1], lw[2], lw[3]};
      *(u32x4*)(lds + 24576 + swz(bnl, bkh * 2)) = v;
      v = (u32x4){lw[4], lw[5], lw[6], lw[7]};
      *(u32x4*)(lds + 24576 + swz(bnl, bkh * 2 + 1)) = v;
    }
    __syncthreads();
    // prefetch next k-step while MFMAs run
    if (s + 1 < ksteps) { int kn = kt0 + (s + 1) * 32; LOADA(kn); LOADB(kn); }
    // ---- fragments + MFMA ----
    {
      s16x8 fbh[4], fbl[4];
#pragma unroll
      for (int ni = 0; ni < 4; ++ni) {
        fbh[ni] = *(const s16x8*)(lds + 16384 + swz(wn + ni * 16 + fr, fq));
        fbl[ni] = *(const s16x8*)(lds + 24576 + swz(wn + ni * 16 + fr, fq));
      }
#pragma unroll
      for (int mi = 0; mi < 4; ++mi) {
        s16x8 fah = *(const s16x8*)(lds + swz(wm + mi * 16 + fr, fq));
        s16x8 fal = *(const s16x8*)(lds + 8192 + swz(wm + mi * 16 + fr, fq));
#pragma unroll
        for (int ni = 0; ni < 4; ++ni) {
          acc[mi][ni] = __builtin_amdgcn_mfma_f32_16x16x32_bf16(fah, fbh[ni], acc[mi][ni], 0, 0, 0);
          acc[mi][ni] = __builtin_amdgcn_mfma_f32_16x16x32_bf16(fah, fbl[ni], acc[mi][ni], 0, 0, 0);
          acc[mi][ni] = __builtin_amdgcn_mfma_f32_16x16x32_bf16(fal, fbh[ni], acc[mi][ni], 0, 0, 0);
        }
      }
    }
  }
#undef LOADA
#undef LOADB
  // epilogue: C/D layout col=lane&15, row=(lane>>4)*4+reg  [m89/m91]
#pragma unroll
  for (int mi = 0; mi < 4; ++mi) {
#pragma unroll
    for (int ni = 0; ni < 4; ++ni) {
      int col = n0 + wn + ni * 16 + fr;
      int rowb = m0 + wm + mi * 16 + fq * 4;
#pragma unroll
      for (int rr = 0; rr < 4; ++rr) {
        int m = rowb + rr;
        if (m < M) atomicAdd(&C[(u64)m * N + col], acc[mi][ni][rr]);
      }
    }
  }
}

// ---------------- bias + relu + bf16 hi/lo pack ----------------
__global__ void k_pack(const float* __restrict__ C, const float* __restrict__ bias,
                       u16* __restrict__ H, u16* __restrict__ L, int total, int nmask) {
  int g = blockIdx.x * 256 + threadIdx.x;
  if (g >= total) return;
  float v = C[g] + bias[g & nmask];
  v = v > 0.f ? v : 0.f;
  u16 h, l; bsplit(v, h, l);
  H[g] = h; L[g] = l;
}

// ---------------- final heads: (300x84)+(300x21) from h2 planes ----------------
__global__ __launch_bounds__(128) void k_heads(const u16* __restrict__ H2H,
        const u16* __restrict__ H2L,
        const float* __restrict__ W_reg, const float* __restrict__ b_reg,
        const float* __restrict__ W_cls, const float* __restrict__ b_cls,
        float* __restrict__ out) {
  __shared__ float hrow[4096];
  int m = blockIdx.x;
  int tid = threadIdx.x;
  for (int e = tid; e < 4096; e += 128) {
    u64 idx = (u64)m * 4096 + e;
    hrow[e] = __fadd_rn(bf2f(H2H[idx]), bf2f(H2L[idx]));
  }
  __syncthreads();
  int n = tid;
  if (n < 105) {
    const float* W; int ld, nn;
    if (n < 84) { W = W_reg; ld = 84; nn = n; }
    else { W = W_cls; ld = 21; nn = n - 84; }
    float acc = 0.f;
    for (int k = 0; k < 4096; ++k)
      acc = fmaf(hrow[k], W[(u64)k * ld + nn], acc);
    if (n < 84) out[m * 84 + n] = acc + b_reg[n];
    else out[25200 + m * 21 + nn] = acc + b_cls[nn];
  }
}

extern "C" void kernel_launch(void* const* d_in, const int* in_sizes, int n_in,
                              void* d_out, int out_size, void* d_ws, size_t ws_size,
                              hipStream_t stream) {
  (void)in_sizes; (void)n_in; (void)out_size; (void)ws_size;
  const float* features = (const float*)d_in[0];
  const float* W_conv   = (const float*)d_in[1];
  const float* b_conv   = (const float*)d_in[2];
  const float* W_loc    = (const float*)d_in[3];
  const float* b_loc    = (const float*)d_in[4];
  const float* W_score  = (const float*)d_in[5];
  const float* b_score  = (const float*)d_in[6];
  const float* W_fc1    = (const float*)d_in[7];
  const float* b_fc1    = (const float*)d_in[8];
  const float* W_fc2    = (const float*)d_in[9];
  const float* b_fc2    = (const float*)d_in[10];
  const float* W_cls    = (const float*)d_in[11];
  const float* b_cls    = (const float*)d_in[12];
  const float* W_reg    = (const float*)d_in[13];
  const float* b_reg    = (const float*)d_in[14];

  char* ws = (char*)d_ws;
  float* out    = (float*)d_out;
  float* h      = (float*)(ws + WS_H);
  float* locs   = (float*)(ws + WS_LOCS);
  float* scores = (float*)(ws + WS_SCORES);
  float* roi    = (float*)(ws + WS_ROI);
  u64*   keys   = (u64*)(ws + WS_KEYS);
  u32*   cnt    = (u32*)(ws + WS_CTRL);
  u64*   ctrlT  = (u64*)(ws + WS_CTRL + 8);
  u64*   skeys  = (u64*)(ws + WS_SKEYS);
  float* boxes  = (float*)(ws + WS_BOXES);
  u64*   validw = (u64*)(ws + WS_VALIDW);
  u64*   mask   = (u64*)(ws + WS_MASK);
  float* rois   = (float*)(ws + WS_ROIS);
  float* Wt     = (float*)(ws + WS_WT);
  float* featT  = (float*)(ws + WS_FEATT);
  u16*   Phi    = (u16*)(ws + WS_PH);
  u16*   Plo    = (u16*)(ws + WS_PL);
  float* Cacc   = (float*)(ws + WS_CACC);
  u16*   H1H    = (u16*)(ws + WS_H1H);
  u16*   H1L    = (u16*)(ws + WS_H1L);
  u16*   H2H    = (u16*)(ws + WS_H2H);
  u16*   H2L    = (u16*)(ws + WS_H2L);

  hipMemsetAsync(ws + WS_CTRL, 0, 256, stream);
  hipMemsetAsync(ws + WS_SKEYS, 0, 4096 * 8, stream);

  k_transpose<<<dim3(288, 16), dim3(32, 8), 0, stream>>>(W_conv, Wt, 512, 9216);
  k_transpose<<<dim3(79, 32),  dim3(32, 8), 0, stream>>>(features, featT, 1024, 2500);
  k_conv3x3<<<dim3(40, 8), 256, 0, stream>>>(Wt, features, b_conv, h);
  k_rpn1x1<<<dim3(40, 4), 256, 0, stream>>>(h, W_loc, b_loc, W_score, b_score, locs, scores);
  k_decode<<<dim3(88), 256, 0, stream>>>(locs, scores, roi, keys, out);
  k_select<<<1, 1024, 0, stream>>>(keys, ctrlT);
  k_compact<<<88, 256, 0, stream>>>(keys, ctrlT, cnt, skeys);
  k_sortgather<<<1, 1024, 0, stream>>>(skeys, roi, boxes, validw);
  k_mask<<<dim3(47, 12), 256, 0, stream>>>(boxes, mask);
  k_nms<<<1, 64, 0, stream>>>(mask, validw, boxes, rois);
  k_roialign<<<2400, 256, 0, stream>>>(rois, featT, Phi, Plo);

  // fc1: 300x50176 @ 50176x4096
  hipMemsetAsync(ws + WS_CACC, 0, 300 * 4096 * 4, stream);
  k_gemm_hl<<<dim3(3, 32, 8), 256, 0, stream>>>(Phi, Plo, W_fc1, Cacc, 300, 4096, 50176, 196);
  k_pack<<<4800, 256, 0, stream>>>(Cacc, b_fc1, H1H, H1L, 300 * 4096, 4095);
  // fc2: 300x4096 @ 4096x4096
  hipMemsetAsync(ws + WS_CACC, 0, 300 * 4096 * 4, stream);
  k_gemm_hl<<<dim3(3, 32, 4), 256, 0, stream>>>(H1H, H1L, W_fc2, Cacc, 300, 4096, 4096, 32);
  k_pack<<<4800, 256, 0, stream>>>(Cacc, b_fc2, H2H, H2L, 300 * 4096, 4095);

  k_heads<<<300, 128, 0, stream>>>(H2H, H2L, W_reg, b_reg, W_cls, b_cls, out);
}